// Round 1
// baseline (613.976 us; speedup 1.0000x reference)
//
#include <hip/hip_runtime.h>

// Voxelization on MI355X.
// Outputs (flat float32, in return order):
//   voxels [60000,64,4], coors [60000,3] (z,y,x), npv [60000], voxel_num [1]
// Strategy: hash table over voxel linear ids (no sort).
//   rank  = prefix-sum over "i is min-index point of its voxel"  (first-occurrence order)
//   pos   = #{j in same voxel : j < i} from per-slot index list (K entries; counts are
//           Poisson(0.022) so max count ~5; brute-force fallback if count > K)

#define MAXV 60000
#define MAXP 64
#define CHUNK 2048          // items per scan block (256 thr x 8)
#define SCAN_T 1024         // threads in partial-scan block (handles up to 2048 partials)

__device__ __forceinline__ int compute_lin(float x, float y, float z,
                                           int* ogx, int* ogy, int* ogz) {
  // Must match numpy float32: floor((p - lo) / vs), then int bounds check.
  float fx = floorf((x - 0.0f) / 0.05f);
  float fy = floorf((y - (-40.0f)) / 0.05f);
  float fz = floorf((z - (-3.0f)) / 0.1f);
  if (!(fx >= 0.0f && fx < 1408.0f &&
        fy >= 0.0f && fy < 1600.0f &&
        fz >= 0.0f && fz < 40.0f))
    return -1;
  int gx = (int)fx, gy = (int)fy, gz = (int)fz;
  if (ogx) { *ogx = gx; *ogy = gy; *ogz = gz; }
  return (gx * 1600 + gy) * 40 + gz;
}

// ---- P1: hash insert + per-slot aggregates -------------------------------
__global__ void k_build(const float4* __restrict__ pts, int N,
                        int* __restrict__ keys, int* __restrict__ firstIdx,
                        int* __restrict__ cnt, int* __restrict__ lists,
                        int* __restrict__ pslot, int tmask, int K) {
  int i = blockIdx.x * 256 + threadIdx.x;
  if (i >= N) return;
  float4 p = pts[i];
  int lin = compute_lin(p.x, p.y, p.z, nullptr, nullptr, nullptr);
  if (lin < 0) { pslot[i] = -1; return; }
  unsigned h = (unsigned)lin * 2654435761u;
  int s = (int)((h ^ (h >> 15)) & (unsigned)tmask);
  while (true) {
    int prev = atomicCAS(&keys[s], -1, lin);
    if (prev == -1 || prev == lin) break;
    s = (s + 1) & tmask;
  }
  pslot[i] = s;
  atomicMin(&firstIdx[s], i);
  int a = atomicAdd(&cnt[s], 1);
  if (a < K) lists[s * K + a] = i;
}

// ---- P2a: per-block count of "first point of voxel" flags ----------------
__global__ void k_flag_reduce(const int* __restrict__ pslot,
                              const int* __restrict__ firstIdx,
                              int N, int* __restrict__ partials) {
  int tid = threadIdx.x;
  int base = blockIdx.x * CHUNK + tid * 8;
  int sum = 0;
#pragma unroll
  for (int j = 0; j < 8; j++) {
    int i = base + j;
    if (i < N) {
      int s = pslot[i];
      if (s >= 0 && firstIdx[s] == i) sum++;
    }
  }
  __shared__ int sd[256];
  sd[tid] = sum;
  __syncthreads();
  for (int off = 128; off > 0; off >>= 1) {
    if (tid < off) sd[tid] += sd[tid + off];
    __syncthreads();
  }
  if (tid == 0) partials[blockIdx.x] = sd[0];
}

// ---- P2b: single-block exclusive scan of partials, write voxel_num -------
__global__ void k_scan_partials(int* __restrict__ partials, int NB,
                                float* __restrict__ outNum) {
  int tid = threadIdx.x;
  int i0 = 2 * tid, i1 = 2 * tid + 1;
  int a = (i0 < NB) ? partials[i0] : 0;
  int b = (i1 < NB) ? partials[i1] : 0;
  int s = a + b;
  __shared__ int sd[SCAN_T];
  sd[tid] = s;
  __syncthreads();
  for (int off = 1; off < SCAN_T; off <<= 1) {
    int v = (tid >= off) ? sd[tid - off] : 0;
    __syncthreads();
    sd[tid] += v;
    __syncthreads();
  }
  int incl = sd[tid];
  int exclPair = incl - s;
  if (i0 < NB) partials[i0] = exclPair;
  if (i1 < NB) partials[i1] = exclPair + a;
  if (tid == SCAN_T - 1) {
    int total = incl;
    outNum[0] = (float)(total < MAXV ? total : MAXV);
  }
}

// ---- P2c: assign ranks; write coors + npv for ranks < MAXV ---------------
__global__ void k_rank(const float4* __restrict__ pts,
                       const int* __restrict__ pslot,
                       const int* __restrict__ firstIdx,
                       const int* __restrict__ cnt,
                       const int* __restrict__ partials,
                       int* __restrict__ slotRank,
                       float* __restrict__ outCoors, float* __restrict__ outNpv,
                       int N) {
  int tid = threadIdx.x;
  int base = blockIdx.x * CHUNK + tid * 8;
  int f[8], ps[8];
  int sum = 0;
#pragma unroll
  for (int j = 0; j < 8; j++) {
    int i = base + j;
    int s = (i < N) ? pslot[i] : -1;
    ps[j] = s;
    int fl = (s >= 0 && firstIdx[s] == i) ? 1 : 0;
    f[j] = fl;
    sum += fl;
  }
  __shared__ int sd[256];
  sd[tid] = sum;
  __syncthreads();
  for (int off = 1; off < 256; off <<= 1) {
    int v = (tid >= off) ? sd[tid - off] : 0;
    __syncthreads();
    sd[tid] += v;
    __syncthreads();
  }
  int run = partials[blockIdx.x] + sd[tid] - sum;  // exclusive before this thread
#pragma unroll
  for (int j = 0; j < 8; j++) {
    if (f[j]) {
      int i = base + j;
      int s = ps[j];
      int r = run++;
      slotRank[s] = r;
      if (r < MAXV) {
        float4 p = pts[i];
        int gx, gy, gz;
        compute_lin(p.x, p.y, p.z, &gx, &gy, &gz);
        outCoors[r * 3 + 0] = (float)gz;
        outCoors[r * 3 + 1] = (float)gy;
        outCoors[r * 3 + 2] = (float)gx;
        int c = cnt[s];
        outNpv[r] = (float)(c < MAXP ? c : MAXP);
      }
    }
  }
}

// ---- P3: scatter points into voxels[rank][pos] ---------------------------
__global__ void k_scatter(const float4* __restrict__ pts,
                          const int* __restrict__ pslot,
                          const int* __restrict__ slotRank,
                          const int* __restrict__ cnt,
                          const int* __restrict__ lists,
                          float4* __restrict__ outVox, int N, int K) {
  int i = blockIdx.x * 256 + threadIdx.x;
  if (i >= N) return;
  int s = pslot[i];
  if (s < 0) return;
  int r = slotRank[s];
  if (r >= MAXV) return;
  int c = cnt[s];
  int pos = 0;
  if (c <= K) {
    for (int t = 0; t < c; t++) pos += (lists[s * K + t] < i) ? 1 : 0;
  } else {
    // Essentially-never-taken exact fallback (count > K).
    float4 me = pts[i];
    int mylin = compute_lin(me.x, me.y, me.z, nullptr, nullptr, nullptr);
    for (int j = 0; j < i; j++) {
      float4 q = pts[j];
      int lj = compute_lin(q.x, q.y, q.z, nullptr, nullptr, nullptr);
      pos += (lj == mylin) ? 1 : 0;
    }
  }
  if (pos >= MAXP) return;
  float4 p = pts[i];
  outVox[(size_t)r * MAXP + pos] = p;
}

extern "C" void kernel_launch(void* const* d_in, const int* in_sizes, int n_in,
                              void* d_out, int out_size, void* d_ws, size_t ws_size,
                              hipStream_t stream) {
  const float4* pts = (const float4*)d_in[0];
  int N = in_sizes[0] / 4;

  float* out = (float*)d_out;
  float* outVox = out;                                    // 60000*64*4
  float* outCoors = out + (size_t)MAXV * MAXP * 4;        // +15,360,000
  float* outNpv = outCoors + (size_t)MAXV * 3;            // +180,000
  float* outNum = outNpv + MAXV;                          // +60,000

  // ---- workspace layout (tiered to fit ws_size) ----
  long long ts = 1LL << 22;
  int K = 8;
  auto need = [&](long long t, int k) -> long long {
    return t * 4 * 4 + t * (long long)k * 4 + (long long)N * 4 + 8192 * 4 + 256;
  };
  if ((long long)ws_size < need(1LL << 22, 8)) { ts = 1LL << 22; K = 4; }
  if ((long long)ws_size < need(ts, K)) { ts = 1LL << 21; K = 4; }
  int tmask = (int)(ts - 1);

  char* w = (char*)d_ws;
  int* keys = (int*)w;              w += ts * 4;
  int* firstIdx = (int*)w;          w += ts * 4;
  int* cnt = (int*)w;               w += ts * 4;
  int* slotRank = (int*)w;          w += ts * 4;
  int* lists = (int*)w;             w += ts * (long long)K * 4;
  int* pslot = (int*)w;             w += (long long)N * 4;
  int* partials = (int*)w;

  // ---- init (ws/d_out are poisoned 0xAA before every timed launch) ----
  hipMemsetAsync(d_out, 0, (size_t)out_size * sizeof(float), stream);
  hipMemsetAsync(keys, 0xFF, (size_t)ts * 4, stream);      // -1 = empty
  hipMemsetAsync(firstIdx, 0x7F, (size_t)ts * 4, stream);  // 0x7F7F7F7F > N
  hipMemsetAsync(cnt, 0x00, (size_t)ts * 4, stream);

  int nbP = (N + 255) / 256;
  int NB = (N + CHUNK - 1) / CHUNK;  // <= 2048 for N <= 4.19M

  k_build<<<nbP, 256, 0, stream>>>(pts, N, keys, firstIdx, cnt, lists, pslot, tmask, K);
  k_flag_reduce<<<NB, 256, 0, stream>>>(pslot, firstIdx, N, partials);
  k_scan_partials<<<1, SCAN_T, 0, stream>>>(partials, NB, outNum);
  k_rank<<<NB, 256, 0, stream>>>(pts, pslot, firstIdx, cnt, partials, slotRank,
                                 outCoors, outNpv, N);
  k_scatter<<<nbP, 256, 0, stream>>>(pts, pslot, slotRank, cnt, lists,
                                     (float4*)outVox, N, K);
}